// Round 2
// baseline (205.238 us; speedup 1.0000x reference)
//
#include <hip/hip_runtime.h>
#include <hip/hip_bf16.h>

// PCNN recurrence, wave-synchronous version: one WAVE owns a 640-elem region
// (512 outputs + 64-elem halo each side; halo >= T=64 so waves are fully
// independent). No LDS, no __syncthreads — neighbor exchange is in-register
// via __shfl rotations. This removes the per-step barrier drain
// (s_waitcnt vmcnt(0) before s_barrier) that made round 1 latency-bound.
//
// Layout: slot k (k=0..4) covers region elems [128k, 128k+128); lane i holds
// elems 128k+2i, 128k+2i+1 as a float2 -> coalesced 512B global accesses.

#define TT 64
#define LL 8192
#define CC 512
#define HH 64
#define RR 640
#define KS 5            // float2 slots per lane = RR / 128
#define NCHUNK 16       // LL / CC

__device__ __forceinline__ float fsigmoid(float z) {
    float ex = __expf(-z);
    return __fdividef(1.0f, 1.0f + ex);
}

__global__ __launch_bounds__(128) void pcnn_wave_kernel(
    const float* __restrict__ x, const float* __restrict__ wptr,
    float* __restrict__ out)
{
    const int lane = threadIdx.x & 63;
    const int tile = blockIdx.x * 2 + (threadIdx.x >> 6);  // 512 wave-tiles
    const int chunk = tile & (NCHUNK - 1);
    const int b     = tile >> 4;

    const float w0 = wptr[0], w1 = wptr[1], w2 = wptr[2];
    const float df = 0.90483741803595957f;  // exp(-0.1)
    const float dl = 0.36787944117144233f;  // exp(-1)
    const float de = 0.36787944117144233f;

    const int gbase = chunk * CC - HH;      // global col of region elem 0

    int  col[KS];     // global col of this lane's pair in slot k
    bool vz[KS];      // pair inside [0, LL)?  (pairs never straddle the edge)
    bool st[KS];      // pair inside the central stored region?
    #pragma unroll
    for (int k = 0; k < KS; ++k) {
        const int r = 128 * k + 2 * lane;   // region-local index
        col[k] = gbase + r;
        vz[k]  = (col[k] >= 0) && (col[k] < LL);
        st[k]  = (r >= HH) && (r < HH + CC);
    }

    const float* xrow = x + (size_t)b * TT * LL;
    float*       orow = out + (size_t)b * TT * LL;

    // depth-2 x prefetch
    float2 xb[2][KS];
    #pragma unroll
    for (int k = 0; k < KS; ++k)
        xb[0][k] = vz[k] ? *(const float2*)(xrow + col[k]) : make_float2(0.f, 0.f);
    #pragma unroll
    for (int k = 0; k < KS; ++k)
        xb[1][k] = vz[k] ? *(const float2*)(xrow + LL + col[k]) : make_float2(0.f, 0.f);

    float2 f[KS], l[KS], e[KS], y[KS];
    #pragma unroll
    for (int k = 0; k < KS; ++k) {
        f[k] = make_float2(0.f, 0.f);
        l[k] = make_float2(0.f, 0.f);
        e[k] = make_float2(10.f, 10.f);
        y[k] = make_float2(0.f, 0.f);
    }

    for (int t = 0; t < TT; ++t) {
        const int cur = t & 1;
        float2 xc[KS];
        #pragma unroll
        for (int k = 0; k < KS; ++k) xc[k] = xb[cur][k];

        // issue prefetch for t+2 immediately (independent of compute)
        if (t + 2 < TT) {
            const float* xnxt = xrow + (size_t)(t + 2) * LL;
            #pragma unroll
            for (int k = 0; k < KS; ++k)
                xb[cur][k] = vz[k] ? *(const float2*)(xnxt + col[k]) : make_float2(0.f, 0.f);
        }

        // in-register neighbor exchange (old y values)
        float rl[KS], rr[KS], yl[KS], yr[KS];
        #pragma unroll
        for (int k = 0; k < KS; ++k) {
            rl[k] = __shfl(y[k].y, (lane + 63) & 63, 64);  // lane i <- lane i-1 (.y)
            rr[k] = __shfl(y[k].x, (lane + 1) & 63, 64);   // lane i <- lane i+1 (.x)
        }
        #pragma unroll
        for (int k = 0; k < KS; ++k) {
            yl[k] = (lane == 0)  ? (k > 0      ? rl[k - 1] : 0.f) : rl[k];
            yr[k] = (lane == 63) ? (k < KS - 1 ? rr[k + 1] : 0.f) : rr[k];
        }

        #pragma unroll
        for (int k = 0; k < KS; ++k) {
            f[k].x = df * f[k].x + xc[k].x + (w0 * yl[k] + w1 * y[k].x + w2 * y[k].y);
            f[k].y = df * f[k].y + xc[k].y + (w0 * y[k].x + w1 * y[k].y + w2 * yr[k]);
            l[k].x = dl * l[k].x + (yl[k] + y[k].y);
            l[k].y = dl * l[k].y + (y[k].x + yr[k]);
            const float u0 = f[k].x * (1.0f + 0.5f * l[k].x);
            const float u1 = f[k].y * (1.0f + 0.5f * l[k].y);
            e[k].x = de * e[k].x + 10.0f * y[k].x;
            e[k].y = de * e[k].y + 10.0f * y[k].y;
            y[k].x = vz[k] ? fsigmoid(u0 - e[k].x) : 0.f;
            y[k].y = vz[k] ? fsigmoid(u1 - e[k].y) : 0.f;
        }

        float* orowt = orow + (size_t)t * LL;
        #pragma unroll
        for (int k = 0; k < KS; ++k)
            if (st[k]) *(float2*)(orowt + col[k]) = y[k];
    }
}

extern "C" void kernel_launch(void* const* d_in, const int* in_sizes, int n_in,
                              void* d_out, int out_size, void* d_ws, size_t ws_size,
                              hipStream_t stream) {
    const float* x = (const float*)d_in[0];
    const float* w = (const float*)d_in[1];
    float* out = (float*)d_out;
    pcnn_wave_kernel<<<dim3(256), dim3(128), 0, stream>>>(x, w, out);
}

// Round 3
// 128.306 us; speedup vs baseline: 1.5996x; 1.5996x over previous
//
#include <hip/hip_runtime.h>
#include <hip/hip_bf16.h>

// PCNN recurrence, wave-synchronous v2.
// One WAVE owns R=256 region elems (C=128 stored outputs + 64-elem halo each
// side; halo >= T=64 so waves are fully independent — no barriers ever).
// Lane i holds region elems {2i,2i+1} (slot0) and {128+2i,128+2i+1} (slot1)
// as float2 -> coalesced 512B global accesses per slot.
// Neighbor exchange is 4 ds_bpermute per step, in-register.
// Round-2 fix: prefetch ring p[4][2] indexed ONLY by compile-time constants
// inside an unroll-4 loop (round 2's dynamic cur-index demoted the array to
// LDS: LDS_Block_Size=10240, 1.2M bank conflicts); 2048 waves (8/CU) instead
// of 512 (2/CU) to hide the per-step dependence chain.

#define TT 64
#define LL 8192
#define CC 128
#define HH 64
#define NCHUNK 64   // LL / CC

typedef float v2f __attribute__((ext_vector_type(2)));

__device__ __forceinline__ float bperm(int idx, float v) {
    return __int_as_float(__builtin_amdgcn_ds_bpermute(idx, __float_as_int(v)));
}
__device__ __forceinline__ float fsigmoid(float z) {
    return __fdividef(1.0f, 1.0f + __expf(-z));
}

__global__ __launch_bounds__(256) void pcnn3_kernel(
    const float* __restrict__ x, const float* __restrict__ wptr,
    float* __restrict__ out)
{
    const int lane = threadIdx.x & 63;
    const int tile = blockIdx.x * 4 + (threadIdx.x >> 6);  // 2048 wave-tiles
    const int chunk = tile & (NCHUNK - 1);
    const int b     = tile >> 6;

    const float w0 = wptr[0], w1 = wptr[1], w2 = wptr[2];
    const float df = 0.90483741803595957f;  // exp(-0.1)
    const float dl = 0.36787944117144233f;  // exp(-1)
    const float de = 0.36787944117144233f;

    const int r0 = 2 * lane;                 // slot0 region idx; slot1 = r0+128
    const int c0 = chunk * CC - HH + r0;     // global col, slot0
    const int c1 = c0 + 128;                 // global col, slot1
    const bool vz0 = ((unsigned)c0 < (unsigned)LL);
    const bool vz1 = ((unsigned)c1 < (unsigned)LL);
    const bool st0 = (r0 >= HH);             // lanes 32..63 store slot0
    const bool st1 = (r0 < HH);              // lanes 0..31 store slot1
    const int cc0 = min(max(c0, 0), LL - 2); // clamped (safe) load cols
    const int cc1 = min(max(c1, 0), LL - 2);

    const float* xbase = x + (size_t)b * TT * LL;
    const float* xp0 = xbase + cc0;
    const float* xp1 = xbase + cc1;
    float* op0 = out + (size_t)b * TT * LL + c0;   // valid whenever st0
    float* op1 = op0 + 128;                        // valid whenever st1

    const int lm1 = ((lane + 63) & 63) << 2;  // bpermute byte idx: pull lane-1
    const int lp1 = ((lane + 1) & 63) << 2;   // pull lane+1

    // prefetch ring: rows t..t+3 (compile-time indices only!)
    v2f p[4][2];
    #pragma unroll
    for (int j = 0; j < 4; ++j) {
        p[j][0] = *(const v2f*)(xp0 + (size_t)j * LL);
        p[j][1] = *(const v2f*)(xp1 + (size_t)j * LL);
    }

    v2f f0 = {0.f, 0.f}, f1 = {0.f, 0.f};
    v2f l0 = {0.f, 0.f}, l1 = {0.f, 0.f};
    v2f e0 = {10.f, 10.f}, e1 = {10.f, 10.f};
    v2f y0 = {0.f, 0.f}, y1 = {0.f, 0.f};

    auto step = [&](v2f xa, v2f xb, float* os0, float* os1) {
        // neighbor exchange (old y)
        float rl0 = bperm(lm1, y0.y), rl1 = bperm(lm1, y1.y);
        float rr0 = bperm(lp1, y0.x), rr1 = bperm(lp1, y1.x);
        float yl0 = (lane == 0)  ? 0.f : rl0;
        float yl1 = (lane == 0)  ? rl0 : rl1;  // lane0 wrap = slot0 lane63 .y
        float yr1 = (lane == 63) ? 0.f : rr1;
        float yr0 = (lane == 63) ? rr1 : rr0;  // lane63 wrap = slot1 lane0 .x

        f0.x = df * f0.x + xa.x + (w0 * yl0  + w1 * y0.x + w2 * y0.y);
        f0.y = df * f0.y + xa.y + (w0 * y0.x + w1 * y0.y + w2 * yr0);
        f1.x = df * f1.x + xb.x + (w0 * yl1  + w1 * y1.x + w2 * y1.y);
        f1.y = df * f1.y + xb.y + (w0 * y1.x + w1 * y1.y + w2 * yr1);
        l0.x = dl * l0.x + (yl0  + y0.y);
        l0.y = dl * l0.y + (y0.x + yr0);
        l1.x = dl * l1.x + (yl1  + y1.y);
        l1.y = dl * l1.y + (y1.x + yr1);
        float u00 = f0.x * (1.0f + 0.5f * l0.x);
        float u01 = f0.y * (1.0f + 0.5f * l0.y);
        float u10 = f1.x * (1.0f + 0.5f * l1.x);
        float u11 = f1.y * (1.0f + 0.5f * l1.y);
        e0.x = de * e0.x + 10.0f * y0.x;
        e0.y = de * e0.y + 10.0f * y0.y;
        e1.x = de * e1.x + 10.0f * y1.x;
        e1.y = de * e1.y + 10.0f * y1.y;
        y0.x = vz0 ? fsigmoid(u00 - e0.x) : 0.f;
        y0.y = vz0 ? fsigmoid(u01 - e0.y) : 0.f;
        y1.x = vz1 ? fsigmoid(u10 - e1.x) : 0.f;
        y1.y = vz1 ? fsigmoid(u11 - e1.y) : 0.f;

        if (st0) __builtin_nontemporal_store(y0, (v2f*)os0);
        if (st1) __builtin_nontemporal_store(y1, (v2f*)os1);
    };

    const float* xl0 = xp0 + 4 * (size_t)LL;  // row t+4 at loop top
    const float* xl1 = xp1 + 4 * (size_t)LL;
    float* os0 = op0;
    float* os1 = op1;

    for (int t = 0; t < TT; t += 4) {
        // loads this iteration target rows t+4..t+7; valid iff t+8 <= TT.
        // last iteration: redirect to row 0 (dummy, values never consumed).
        const float* a0 = (t + 8 <= TT) ? xl0 : xp0;
        const float* a1 = (t + 8 <= TT) ? xl1 : xp1;
        #pragma unroll
        for (int j = 0; j < 4; ++j) {
            step(p[j][0], p[j][1], os0, os1);
            p[j][0] = *(const v2f*)(a0 + (size_t)j * LL);
            p[j][1] = *(const v2f*)(a1 + (size_t)j * LL);
            os0 += LL;
            os1 += LL;
        }
        xl0 += 4 * (size_t)LL;
        xl1 += 4 * (size_t)LL;
    }
}

extern "C" void kernel_launch(void* const* d_in, const int* in_sizes, int n_in,
                              void* d_out, int out_size, void* d_ws, size_t ws_size,
                              hipStream_t stream) {
    const float* x = (const float*)d_in[0];
    const float* w = (const float*)d_in[1];
    float* out = (float*)d_out;
    // 2048 wave-tiles = 512 blocks x 4 waves; no LDS, no barriers.
    pcnn3_kernel<<<dim3(512), dim3(256), 0, stream>>>(x, w, out);
}

// Round 4
// 127.057 us; speedup vs baseline: 1.6153x; 1.0098x over previous
//
#include <hip/hip_runtime.h>
#include <hip/hip_bf16.h>

// PCNN recurrence, wave-synchronous v3.
// One WAVE owns R=256 region elems (C=128 stored + 64-halo each side, halo>=T
// so waves are independent — no barriers, no LDS arrays). Lane i holds region
// elems {2i,2i+1} (slot0) and {128+2i,128+2i+1} (slot1) as float2.
// Exchange = 4 ds_bpermute/step, in-register.
// v3 fixes vs round 3 (50us, VALUBusy 45%, HBM 2.2TB/s -> stall-bound):
//  - plain stores (NT stores retired at HBM ~900cyc, inflating the FIFO
//    vmcnt waits for x-prefetch consumption)
//  - 8-deep x prefetch ring (8-step slack vs 4)
//  - single merged unconditional store per lane (was 2 predicated)

#define TT 64
#define LL 8192
#define CC 128
#define HH 64
#define NCHUNK 64   // LL / CC

typedef float v2f __attribute__((ext_vector_type(2)));

__device__ __forceinline__ float bperm(int idx, float v) {
    return __int_as_float(__builtin_amdgcn_ds_bpermute(idx, __float_as_int(v)));
}
__device__ __forceinline__ float fsigmoid(float z) {
    return __fdividef(1.0f, 1.0f + __expf(-z));
}

__global__ __launch_bounds__(256) void pcnn4_kernel(
    const float* __restrict__ x, const float* __restrict__ wptr,
    float* __restrict__ out)
{
    const int lane = threadIdx.x & 63;
    const int tile = blockIdx.x * 4 + (threadIdx.x >> 6);  // 2048 wave-tiles
    const int chunk = tile & (NCHUNK - 1);
    const int b     = tile >> 6;

    const float w0 = wptr[0], w1 = wptr[1], w2 = wptr[2];
    const float df = 0.90483741803595957f;  // exp(-0.1)
    const float dl = 0.36787944117144233f;  // exp(-1)
    const float de = 0.36787944117144233f;

    const int r0 = 2 * lane;                 // slot0 region idx; slot1 = r0+128
    const int c0 = chunk * CC - HH + r0;     // global col, slot0
    const int c1 = c0 + 128;                 // global col, slot1
    const bool vz0 = ((unsigned)c0 < (unsigned)LL);
    const bool vz1 = ((unsigned)c1 < (unsigned)LL);
    const int cc0 = min(max(c0, 0), LL - 2); // clamped (always-safe) load cols
    const int cc1 = min(max(c1, 0), LL - 2);

    const float* xbase = x + (size_t)b * TT * LL;
    const float* xp0 = xbase + cc0;
    const float* xp1 = xbase + cc1;

    // merged store: lanes 0..31 write slot1 (cols chunk*128+64+2lane),
    // lanes 32..63 write slot0 (cols chunk*128+2(lane-32)) — one contiguous
    // 512B segment, always in-bounds, unconditional.
    const bool lo = (lane < 32);
    float* op = out + (size_t)b * TT * LL + (lo ? c1 : c0);

    const int lm1 = ((lane + 63) & 63) << 2;  // bpermute byte idx: pull lane-1
    const int lp1 = ((lane + 1) & 63) << 2;   // pull lane+1

    // 8-deep prefetch ring: rows t..t+7 (compile-time indices only)
    v2f p0[8], p1[8];
    #pragma unroll
    for (int j = 0; j < 8; ++j) {
        p0[j] = *(const v2f*)(xp0 + (size_t)j * LL);
        p1[j] = *(const v2f*)(xp1 + (size_t)j * LL);
    }

    v2f f0 = {0.f, 0.f}, f1 = {0.f, 0.f};
    v2f l0 = {0.f, 0.f}, l1 = {0.f, 0.f};
    v2f e0 = {10.f, 10.f}, e1 = {10.f, 10.f};
    v2f y0 = {0.f, 0.f}, y1 = {0.f, 0.f};

    auto step = [&](v2f xa, v2f xb) {
        // neighbor exchange (old y)
        float rl0 = bperm(lm1, y0.y), rl1 = bperm(lm1, y1.y);
        float rr0 = bperm(lp1, y0.x), rr1 = bperm(lp1, y1.x);
        float yl0 = (lane == 0)  ? 0.f : rl0;
        float yl1 = (lane == 0)  ? rl0 : rl1;  // lane0 slot1 left = slot0 ln63 .y
        float yr1 = (lane == 63) ? 0.f : rr1;
        float yr0 = (lane == 63) ? rr1 : rr0;  // lane63 slot0 right = slot1 ln0 .x

        f0.x = df * f0.x + xa.x + (w0 * yl0  + w1 * y0.x + w2 * y0.y);
        f0.y = df * f0.y + xa.y + (w0 * y0.x + w1 * y0.y + w2 * yr0);
        f1.x = df * f1.x + xb.x + (w0 * yl1  + w1 * y1.x + w2 * y1.y);
        f1.y = df * f1.y + xb.y + (w0 * y1.x + w1 * y1.y + w2 * yr1);
        l0.x = dl * l0.x + (yl0  + y0.y);
        l0.y = dl * l0.y + (y0.x + yr0);
        l1.x = dl * l1.x + (yl1  + y1.y);
        l1.y = dl * l1.y + (y1.x + yr1);
        float u00 = f0.x * (1.0f + 0.5f * l0.x);
        float u01 = f0.y * (1.0f + 0.5f * l0.y);
        float u10 = f1.x * (1.0f + 0.5f * l1.x);
        float u11 = f1.y * (1.0f + 0.5f * l1.y);
        e0.x = de * e0.x + 10.0f * y0.x;
        e0.y = de * e0.y + 10.0f * y0.y;
        e1.x = de * e1.x + 10.0f * y1.x;
        e1.y = de * e1.y + 10.0f * y1.y;
        y0.x = vz0 ? fsigmoid(u00 - e0.x) : 0.f;
        y0.y = vz0 ? fsigmoid(u01 - e0.y) : 0.f;
        y1.x = vz1 ? fsigmoid(u10 - e1.x) : 0.f;
        y1.y = vz1 ? fsigmoid(u11 - e1.y) : 0.f;

        v2f yst;
        yst.x = lo ? y1.x : y0.x;
        yst.y = lo ? y1.y : y0.y;
        *(v2f*)op = yst;
        op += LL;
    };

    const float* xl0 = xp0 + 8 * (size_t)LL;  // row t+8 at loop top
    const float* xl1 = xp1 + 8 * (size_t)LL;

    for (int t = 0; t < TT; t += 8) {
        // loads in this iteration target rows t+8..t+15; valid iff t+16 <= TT.
        // Last outer iteration: redirect to row 0 (dummy, never consumed).
        const float* a0 = (t + 16 <= TT) ? xl0 : xp0;
        const float* a1 = (t + 16 <= TT) ? xl1 : xp1;
        #pragma unroll
        for (int j = 0; j < 8; ++j) {
            step(p0[j], p1[j]);
            p0[j] = *(const v2f*)(a0 + (size_t)j * LL);
            p1[j] = *(const v2f*)(a1 + (size_t)j * LL);
        }
        xl0 += 8 * (size_t)LL;
        xl1 += 8 * (size_t)LL;
    }
}

extern "C" void kernel_launch(void* const* d_in, const int* in_sizes, int n_in,
                              void* d_out, int out_size, void* d_ws, size_t ws_size,
                              hipStream_t stream) {
    const float* x = (const float*)d_in[0];
    const float* w = (const float*)d_in[1];
    float* out = (float*)d_out;
    // 2048 wave-tiles = 512 blocks x 4 waves; no LDS, no barriers.
    pcnn4_kernel<<<dim3(512), dim3(256), 0, stream>>>(x, w, out);
}